// Round 8
// baseline (409.758 us; speedup 1.0000x reference)
//
#include <hip/hip_runtime.h>
#include <cmath>

#define BB 16
#define NN 1024
#define MM 1024
#define RPB 32             // rows per block
#define NSLAB 32           // NN / RPB
#define GR 8               // rows per wave-group (4 groups of 4 waves)

static constexpr float INV_TAU = 20.0f;   // 1/0.05
static constexpr float LR   = 0.5f;
static constexpr float B1f  = 0.9f;
static constexpr float B2f  = 0.999f;
static constexpr float EPSA = 1e-8f;
// Clamp the exp ARGUMENT (survives -ffinite-math-only; result-clamp is folded
// away under fast-math — root cause of the R0-R2 inf->NaN failures).
static constexpr float EXP_CAP = 88.0f;

// ---- d_ws layout (floats) ----
// u/mu/vu: Adam-u state, rows exclusively owned by one block.
// vst: PRIVATE per-(b,slab) replicated v-Adam state [BB*NSLAB][3][MM]
//      (identical deterministic trajectories; self-dependency across launches).
// PS/PM: double-buffered slab partials: S[b][slab][col] + slab normalizer Msl.
#define OFF_U    0
#define OFF_MU   16384
#define OFF_VU   32768
#define OFF_VST  49152
#define OFF_PS0  (OFF_VST + BB*NSLAB*3*MM)    // 1,622,016
#define OFF_PS1  (OFF_PS0 + BB*NSLAB*MM)
#define OFF_PM0  (OFF_PS1 + BB*NSLAB*MM)
#define OFF_PM1  (OFF_PM0 + BB*NSLAB)

// ---- zero u-state + v-state (6.5 MB). 6336*256 == OFF_PS0 exactly. ----
__global__ void init_state(float* __restrict__ ws) {
    int i = blockIdx.x * 256 + threadIdx.x;
    ws[i] = 0.0f;
}

// ---- merge previous partials -> v_{t-1} for column `tid`; Adam-v on the
// block's private state; leaves fresh v in vsh[tid]. ----
__device__ __forceinline__ void merge_v(
    const float* __restrict__ pS, const float* __restrict__ pM,
    const float* __restrict__ log_b, float* __restrict__ vstp,
    float* vsh, float* fsh, float* mgsh,
    int b, int tid, int lane, float bcv1, float bcv2)
{
    if ((tid >> 6) == 0) {   // wave 0: slab factors e^{Msl_s - Mg}
        const float m = pM[b * NSLAB + (lane & 31)];   // duplicated in both halves
        float M = m;
#pragma unroll
        for (int off = 16; off; off >>= 1)             // reduce within each 32-half
            M = fmaxf(M, __shfl_xor(M, off, 64));
        if (lane < 32) fsh[lane] = __expf(m - M);
        if (lane == 0) *mgsh = M;
    }
    __syncthreads();
    const float* ps = pS + (size_t)b * NSLAB * MM + tid;
    float acc = 0.f;
#pragma unroll
    for (int s = 0; s < NSLAB; ++s)
        acc = __builtin_fmaf(ps[(size_t)s * MM], fsh[s], acc);
    const float lse = *mgsh + __logf(acc);
    const float vo = vstp[0], mo = vstp[MM], wo = vstp[2 * MM];
    const float gv = (log_b[b * MM + tid] - lse) - vo;
    const float mn = B1f * mo + (1.f - B1f) * gv;
    const float wn = B2f * wo + (1.f - B2f) * gv * gv;
    const float vn = vo + LR * (mn / bcv1) / (sqrtf(wn / bcv2) + EPSA);
    vstp[0] = vn; vstp[MM] = mn; vstp[2 * MM] = wn;
    vsh[tid] = vn;
}

// ---- one Sinkhorn iteration, fully fused ----
// grid (NSLAB, BB) x 1024 threads. Block owns a 32-row slab; wave-group g
// (4 waves) owns rows 8g..8g+7, thread covers 4 cols x 8 rows in registers.
__global__ __launch_bounds__(1024, 4) void iter_kernel(
    const float* __restrict__ la, const float* __restrict__ log_a,
    const float* __restrict__ log_b, float* __restrict__ ws,
    const float* __restrict__ pSr, const float* __restrict__ pMr,
    float* __restrict__ pSw, float* __restrict__ pMw,
    int t, float bcu1, float bcu2, float bcv1, float bcv2)
{
    const int slab = blockIdx.x;
    const int b    = blockIdx.y;
    const int tid  = threadIdx.x;
    const int g    = tid >> 8;
    const int gt   = tid & 255;
    const int lane = tid & 63;
    const int gwave = (tid >> 6) & 3;

    __shared__ float vsh[MM];
    __shared__ float fsh[NSLAB];
    __shared__ float redm[4][4][GR];
    __shared__ float reds[4][4][GR];
    __shared__ float rowm[4][GR];
    __shared__ float suh[4][GR];
    __shared__ float mgsh;          // merge Mg, later reused for Msl
    __shared__ float Sp[4][MM];     // per-group col partials

    float* vstp = ws + OFF_VST + (size_t)(b * NSLAB + slab) * 3 * MM + tid;
    if (t > 1)
        merge_v(pSr, pMr, log_b, vstp, vsh, fsh, &mgsh, b, tid, lane, bcv1, bcv2);
    else
        vsh[tid] = 0.f;   // v_0 = 0; private state stays zeroed by init
    __syncthreads();

    // ---- load slab tile (8 rows x 4 cols per thread), pre-scaled ----
    const int row0 = slab * RPB + g * GR;
    const float* Kb = la + ((size_t)(b * NN + row0)) * MM + 4 * gt;
    float kr[GR][4];
#pragma unroll
    for (int r = 0; r < GR; ++r) {
        const float4 k4 = *(const float4*)(Kb + (size_t)r * MM);
        kr[r][0] = k4.x * INV_TAU; kr[r][1] = k4.y * INV_TAU;
        kr[r][2] = k4.z * INV_TAU; kr[r][3] = k4.w * INV_TAU;
    }
    const float4 v4 = *(const float4*)(vsh + 4 * gt);
    const float vj[4] = {v4.x, v4.y, v4.z, v4.w};

    // ---- row pass: max ----
    float pm[GR];
#pragma unroll
    for (int r = 0; r < GR; ++r)
        pm[r] = fmaxf(fmaxf(kr[r][0] + vj[0], kr[r][1] + vj[1]),
                      fmaxf(kr[r][2] + vj[2], kr[r][3] + vj[3]));
#pragma unroll
    for (int off = 32; off; off >>= 1)
#pragma unroll
        for (int r = 0; r < GR; ++r)
            pm[r] = fmaxf(pm[r], __shfl_xor(pm[r], off, 64));
    if (lane == 0)
#pragma unroll
        for (int r = 0; r < GR; ++r) redm[g][gwave][r] = pm[r];
    __syncthreads();
    if (gt < GR)
        rowm[g][gt] = fmaxf(fmaxf(redm[g][0][gt], redm[g][1][gt]),
                            fmaxf(redm[g][2][gt], redm[g][3][gt]));
    __syncthreads();
    float Mr[GR];
#pragma unroll
    for (int r = 0; r < GR; ++r) Mr[r] = rowm[g][r];

    // ---- row pass: exp-sum + Adam-u ----
    float ps[GR];
#pragma unroll
    for (int r = 0; r < GR; ++r)
        ps[r] = __expf(kr[r][0] + vj[0] - Mr[r]) + __expf(kr[r][1] + vj[1] - Mr[r])
              + __expf(kr[r][2] + vj[2] - Mr[r]) + __expf(kr[r][3] + vj[3] - Mr[r]);
#pragma unroll
    for (int off = 32; off; off >>= 1)
#pragma unroll
        for (int r = 0; r < GR; ++r)
            ps[r] += __shfl_xor(ps[r], off, 64);
    if (lane == 0)
#pragma unroll
        for (int r = 0; r < GR; ++r) reds[g][gwave][r] = ps[r];
    __syncthreads();
    if (gt < GR) {
        const int r  = gt;
        const int gi = b * NN + row0 + r;
        const float S   = reds[g][0][r] + reds[g][1][r] + reds[g][2][r] + reds[g][3][r];
        const float lse = rowm[g][r] + __logf(S);
        const float uo  = ws[OFF_U + gi];
        const float gu  = (log_a[gi] - lse) - uo;
        const float m_  = B1f * ws[OFF_MU + gi] + (1.f - B1f) * gu;
        const float w_  = B2f * ws[OFF_VU + gi] + (1.f - B2f) * gu * gu;
        ws[OFF_MU + gi] = m_;
        ws[OFF_VU + gi] = w_;
        const float un  = uo + LR * (m_ / bcu1) / (sqrtf(w_ / bcu2) + EPSA);
        ws[OFF_U + gi]  = un;
        suh[g][r] = un;
    }
    __syncthreads();

    // ---- slab normalizer: Msl = max over 32 rows of (Mr_i + u_i).
    // Guarantees col-pass arg k+u-Msl <= -v_j (no overflow); underflowed
    // terms are >=80 nats below their column's true max (negligible). ----
    if ((tid >> 6) == 0) {
        const int idx = lane & 31;
        float m = rowm[idx >> 3][idx & 7] + suh[idx >> 3][idx & 7];
#pragma unroll
        for (int off = 16; off; off >>= 1)
            m = fmaxf(m, __shfl_xor(m, off, 64));
        if (lane == 0) mgsh = m;
    }
    __syncthreads();
    const float msl = mgsh;

    // ---- col partials from registers with fresh u ----
    float uu[GR];
#pragma unroll
    for (int r = 0; r < GR; ++r) uu[r] = suh[g][r];
    float s4[4];
#pragma unroll
    for (int j = 0; j < 4; ++j) {
        float s = 0.f;
#pragma unroll
        for (int r = 0; r < GR; ++r) s += __expf(kr[r][j] + uu[r] - msl);
        s4[j] = s;
    }
    *(float4*)(Sp[g] + 4 * gt) = make_float4(s4[0], s4[1], s4[2], s4[3]);
    __syncthreads();
    pSw[(size_t)(b * NSLAB + slab) * MM + tid]
        = Sp[0][tid] + Sp[1][tid] + Sp[2][tid] + Sp[3][tid];
    if (tid == 0) pMw[b * NSLAB + slab] = msl;
}

// ---- final kernel: merge v_10, then out = exp(K + u + v) arg-clamped ----
__global__ __launch_bounds__(1024, 4) void fin_kernel(
    const float* __restrict__ la, const float* __restrict__ log_b,
    float* __restrict__ ws,
    const float* __restrict__ pSr, const float* __restrict__ pMr,
    float* __restrict__ out, float bcv1, float bcv2)
{
    const int slab = blockIdx.x;
    const int b    = blockIdx.y;
    const int tid  = threadIdx.x;
    const int g    = tid >> 8;
    const int gt   = tid & 255;
    const int lane = tid & 63;
    __shared__ float vsh[MM];
    __shared__ float fsh[NSLAB];
    __shared__ float mgsh;

    float* vstp = ws + OFF_VST + (size_t)(b * NSLAB + slab) * 3 * MM + tid;
    merge_v(pSr, pMr, log_b, vstp, vsh, fsh, &mgsh, b, tid, lane, bcv1, bcv2);
    __syncthreads();

    const int row0 = slab * RPB + g * GR;
    const float4 v4 = *(const float4*)(vsh + 4 * gt);
    const float* Kb = la + ((size_t)(b * NN + row0)) * MM + 4 * gt;
    float* Ob = out + ((size_t)(b * NN + row0)) * MM + 4 * gt;
#pragma unroll
    for (int r = 0; r < GR; ++r) {
        const float u = ws[OFF_U + b * NN + row0 + r];
        const float4 k4 = *(const float4*)(Kb + (size_t)r * MM);
        float4 o;
        o.x = __expf(fminf(k4.x * INV_TAU + u + v4.x, EXP_CAP));
        o.y = __expf(fminf(k4.y * INV_TAU + u + v4.y, EXP_CAP));
        o.z = __expf(fminf(k4.z * INV_TAU + u + v4.z, EXP_CAP));
        o.w = __expf(fminf(k4.w * INV_TAU + u + v4.w, EXP_CAP));
        *(float4*)(Ob + (size_t)r * MM) = o;
    }
}

extern "C" void kernel_launch(void* const* d_in, const int* in_sizes, int n_in,
                              void* d_out, int out_size, void* d_ws, size_t ws_size,
                              hipStream_t stream) {
    const float* la    = (const float*)d_in[0];
    const float* log_a = (const float*)d_in[1];
    const float* log_b = (const float*)d_in[2];
    float* out = (float*)d_out;
    float* ws  = (float*)d_ws;
    float* PS[2] = {ws + OFF_PS0, ws + OFF_PS1};
    float* PM[2] = {ws + OFF_PM0, ws + OFF_PM1};

    init_state<<<6336, 256, 0, stream>>>(ws);
    for (int t = 1; t <= 10; ++t) {
        const float bcu1 = 1.f - powf(B1f, (float)t);
        const float bcu2 = 1.f - powf(B2f, (float)t);
        const float bcv1 = (t > 1) ? 1.f - powf(B1f, (float)(t - 1)) : 1.f;
        const float bcv2 = (t > 1) ? 1.f - powf(B2f, (float)(t - 1)) : 1.f;
        // K_t reads partials(t-1) from buffer (t-1)&1, writes partials(t) to t&1
        iter_kernel<<<dim3(NSLAB, BB), 1024, 0, stream>>>(
            la, log_a, log_b, ws,
            PS[(t - 1) & 1], PM[(t - 1) & 1], PS[t & 1], PM[t & 1],
            t, bcu1, bcu2, bcv1, bcv2);
    }
    // K10 wrote buffer 0; fin merges v_10 (bias corrections for t=10)
    fin_kernel<<<dim3(NSLAB, BB), 1024, 0, stream>>>(
        la, log_b, ws, PS[0], PM[0], out,
        1.f - powf(B1f, 10.0f), 1.f - powf(B2f, 10.0f));
}